// Round 16
// baseline (209.040 us; speedup 1.0000x reference)
//
#include <hip/hip_runtime.h>

#define N_NODES 100000
#define N_EDGES 3200000
#define N_FEAT  512
#define HID     16
#define N_CLASS 40

#define BSHIFT  9                      // 512 nodes per bucket
#define BMASK   ((1 << BSHIFT) - 1)
#define NB      196                    // ceil(100000 / 512)
#define CAP     18432                  // padded bucket region (mean 16384, +16 sigma)
#define EPB     4096                   // edges per binning block

#define BIN_BLOCKS  ((N_EDGES + EPB - 1) / EPB)   // 782
#define NT_TILES    (N_NODES / 16)                // 6250 lin1 tiles
#define LIN1_BLOCKS ((NT_TILES + 3) / 4)          // 1563

typedef __attribute__((ext_vector_type(8))) short bf16x8;
typedef __attribute__((ext_vector_type(4))) float f32x4;

__device__ inline short2 split_bf(float v) {
    const unsigned u = __float_as_uint(v);
    const short hi = (short)(u >> 16);
    const float hf = __uint_as_float(u & 0xFFFF0000u);
    const short lo = (short)(__float_as_uint(v - hf) >> 16);
    return make_short2(hi, lo);
}
__device__ inline unsigned short f2bf_rtn(float v) {
    unsigned u = __float_as_uint(v);
    u += 0x7FFFu + ((u >> 16) & 1u);
    return (unsigned short)(u >> 16);
}
__device__ inline float bf2f(unsigned short u) {
    return __uint_as_float(((unsigned)u) << 16);
}

// ================= Fused: CSR binning (blocks 0..781) + lin1 (rest) =========
struct BinSmem {
    int hist[NB]; int lofs[NB]; int base[NB]; int rk[NB];
    int buf[256]; int stage[EPB]; unsigned short sbkt[EPB];
};
struct Lin1Smem { short bfH[16 * 64 * 8]; short bfL[16 * 64 * 8]; };

__device__ void bin_body(char* smemraw,
                         const int* __restrict__ src,
                         const int* __restrict__ dst,
                         int* __restrict__ cursor,
                         int* __restrict__ binned) {
    BinSmem& sm = *(BinSmem*)smemraw;
    const int t = threadIdx.x;
    for (int i = t; i < NB; i += 256) { sm.hist[i] = 0; sm.rk[i] = 0; }
    __syncthreads();

    const int e0 = blockIdx.x * EPB;
    int bk[EPB / 256];
    int vv[EPB / 256];
#pragma unroll
    for (int k = 0; k < EPB / 256; k++) {
        const int e = e0 + k * 256 + t;
        if (e < N_EDGES) {
            const int d = dst[e], s = src[e];
            bk[k] = d >> BSHIFT;
            vv[k] = (s << BSHIFT) | (d & BMASK);
            atomicAdd(&sm.hist[bk[k]], 1);
        } else bk[k] = -1;
    }
    __syncthreads();

    {
        const int v = (t < NB) ? sm.hist[t] : 0;
        sm.buf[t] = v; __syncthreads();
        for (int o = 1; o < 256; o <<= 1) {
            const int a = (t >= o) ? sm.buf[t - o] : 0;
            __syncthreads();
            sm.buf[t] += a;
            __syncthreads();
        }
        if (t < NB) sm.lofs[t] = sm.buf[t] - v;
    }
    if (t < NB && sm.hist[t] > 0)
        sm.base[t] = t * CAP + atomicAdd(&cursor[t], sm.hist[t]);

#pragma unroll
    for (int k = 0; k < EPB / 256; k++) {
        if (bk[k] >= 0) {
            const int r = atomicAdd(&sm.rk[bk[k]], 1);
            const int slot = sm.lofs[bk[k]] + r;
            sm.stage[slot] = vv[k];
            sm.sbkt[slot] = (unsigned short)bk[k];
        }
    }
    __syncthreads();

    const int nloc = min(EPB, N_EDGES - e0);
    for (int s2 = t; s2 < nloc; s2 += 256) {
        const int b = sm.sbkt[s2];
        binned[sm.base[b] + (s2 - sm.lofs[b])] = sm.stage[s2];
    }
}

__device__ void lin1_body(char* smemraw, int lblk,
                          const float* __restrict__ x,
                          const float* __restrict__ w1,
                          const float* __restrict__ b1,
                          unsigned short* __restrict__ xnb,
                          float* __restrict__ normv) {
    Lin1Smem& sm = *(Lin1Smem*)smemraw;
    const int t = threadIdx.x;
    for (int f = t; f < 16 * 64; f += 256) {
        const int kt  = f >> 6;
        const int ln  = f & 63;
        const int col = ln & 15;
        const int k0  = kt * 32 + (ln >> 4) * 8;
        const float4 v0 = *(const float4*)(w1 + col * N_FEAT + k0);
        const float4 v1 = *(const float4*)(w1 + col * N_FEAT + k0 + 4);
        bf16x8 hh, ll;
        short2 r;
        r = split_bf(v0.x); hh[0] = r.x; ll[0] = r.y;
        r = split_bf(v0.y); hh[1] = r.x; ll[1] = r.y;
        r = split_bf(v0.z); hh[2] = r.x; ll[2] = r.y;
        r = split_bf(v0.w); hh[3] = r.x; ll[3] = r.y;
        r = split_bf(v1.x); hh[4] = r.x; ll[4] = r.y;
        r = split_bf(v1.y); hh[5] = r.x; ll[5] = r.y;
        r = split_bf(v1.z); hh[6] = r.x; ll[6] = r.y;
        r = split_bf(v1.w); hh[7] = r.x; ll[7] = r.y;
        ((bf16x8*)sm.bfH)[f] = hh;
        ((bf16x8*)sm.bfL)[f] = ll;
    }
    __syncthreads();

    const int wv   = t >> 6;
    const int l    = t & 63;
    const int tile = lblk * 4 + wv;
    if (tile >= NT_TILES) return;

    const int r0 = tile * 16;
    const float* xp = x + (size_t)(r0 + (l & 15)) * N_FEAT + ((l >> 4) * 8);

    f32x4 acc = {0.f, 0.f, 0.f, 0.f};
    float4 c0 = *(const float4*)(xp);
    float4 c1 = *(const float4*)(xp + 4);
#pragma unroll
    for (int kt = 0; kt < 16; ++kt) {
        float4 n0, n1;
        if (kt < 15) {
            n0 = *(const float4*)(xp + (kt + 1) * 32);
            n1 = *(const float4*)(xp + (kt + 1) * 32 + 4);
        }
        bf16x8 ah, al;
        short2 r;
        r = split_bf(c0.x); ah[0] = r.x; al[0] = r.y;
        r = split_bf(c0.y); ah[1] = r.x; al[1] = r.y;
        r = split_bf(c0.z); ah[2] = r.x; al[2] = r.y;
        r = split_bf(c0.w); ah[3] = r.x; al[3] = r.y;
        r = split_bf(c1.x); ah[4] = r.x; al[4] = r.y;
        r = split_bf(c1.y); ah[5] = r.x; al[5] = r.y;
        r = split_bf(c1.z); ah[6] = r.x; al[6] = r.y;
        r = split_bf(c1.w); ah[7] = r.x; al[7] = r.y;
        const bf16x8 bh = ((const bf16x8*)sm.bfH)[kt * 64 + l];
        const bf16x8 bl = ((const bf16x8*)sm.bfL)[kt * 64 + l];
        acc = __builtin_amdgcn_mfma_f32_16x16x32_bf16(ah, bh, acc, 0, 0, 0);
        acc = __builtin_amdgcn_mfma_f32_16x16x32_bf16(al, bh, acc, 0, 0, 0);
        acc = __builtin_amdgcn_mfma_f32_16x16x32_bf16(ah, bl, acc, 0, 0, 0);
        c0 = n0; c1 = n1;
    }

    const float bias = b1[l & 15];
#pragma unroll
    for (int r = 0; r < 4; ++r) {
        const float v = fmaxf(acc[r] + bias, 0.f);
        float ss = v * v;
        ss += __shfl_xor(ss, 1); ss += __shfl_xor(ss, 2);
        ss += __shfl_xor(ss, 4); ss += __shfl_xor(ss, 8);
        const float nrm = sqrtf(ss);
        const float rn  = 1.f / fmaxf(nrm, 1e-12f);
        const int row = r0 + (l >> 4) * 4 + r;
        xnb[(size_t)row * HID + (l & 15)] = f2bf_rtn(v * rn);
        if ((l & 15) == 0) normv[row] = nrm;
    }
}

__global__ __launch_bounds__(256) void k_bin_lin1(const int* __restrict__ src,
                                                  const int* __restrict__ dst,
                                                  int* __restrict__ cursor,
                                                  int* __restrict__ binned,
                                                  const float* __restrict__ x,
                                                  const float* __restrict__ w1,
                                                  const float* __restrict__ b1,
                                                  unsigned short* __restrict__ xnb,
                                                  float* __restrict__ normv) {
    __shared__ __align__(16) char smem[sizeof(Lin1Smem) > sizeof(BinSmem)
                                       ? sizeof(Lin1Smem) : sizeof(BinSmem)];
    if (blockIdx.x < BIN_BLOCKS)
        bin_body(smem, src, dst, cursor, binned);
    else
        lin1_body(smem, blockIdx.x - BIN_BLOCKS, x, w1, b1, xnb, normv);
}

// ============================== k_csr + degree sort =========================
// Per bucket: per-node counts, scan -> row_start/row_cnt, LDS scatter of srcs
// (coalesced write-back), then a 128-bin counting sort of the bucket's nodes
// by degree -> nodeperm (wave-uniform degrees in agnn, kills divergence).
__global__ __launch_bounds__(512) void k_csr(const int* __restrict__ cursor,
                                             int* __restrict__ binned,
                                             int* __restrict__ row_start,
                                             unsigned short* __restrict__ row_cnt,
                                             int* __restrict__ nodeperm) {
    __shared__ int cnts[512];
    __shared__ int cur[512];
    __shared__ int buf[512];
    __shared__ int lcsr[CAP];

    const int t = threadIdx.x;
    const int b = blockIdx.x;
    const int s0 = b * CAP;
    const int n = cursor[b];

    cnts[t] = 0;
    __syncthreads();
    for (int i = t; i < n; i += 512)
        atomicAdd(&cnts[binned[s0 + i] & BMASK], 1);
    __syncthreads();

    {
        const int v = cnts[t];
        buf[t] = v; __syncthreads();
        for (int o = 1; o < 512; o <<= 1) {
            const int a = (t >= o) ? buf[t - o] : 0;
            __syncthreads();
            buf[t] += a;
            __syncthreads();
        }
        cur[t] = buf[t] - v;
        const int node = (b << BSHIFT) + t;
        if (node < N_NODES) {
            row_start[node] = s0 + cur[t];
            row_cnt[node]   = (unsigned short)v;
        }
    }
    __syncthreads();

    for (int i = t; i < n; i += 512) {
        const int v = binned[s0 + i];
        const int p = atomicAdd(&cur[v & BMASK], 1);
        lcsr[p] = v >> BSHIFT;
    }
    __syncthreads();

    for (int i = t; i < n; i += 512) binned[s0 + i] = lcsr[i];

    // ---- degree counting sort (cnts[] still holds per-node degrees) ----
    __syncthreads();
    if (t < 128) buf[t] = 0;
    __syncthreads();
    const int nodeT = (b << BSHIFT) + t;
    const bool aliveT = nodeT < N_NODES;
    int myb = 0;
    if (aliveT) {
        myb = min(cnts[t], 127);
        atomicAdd(&buf[myb], 1);
    }
    __syncthreads();
    if (t < 128) cur[t] = buf[t];
    __syncthreads();
    for (int o = 1; o < 128; o <<= 1) {
        int a = 0;
        if (t < 128 && t >= o) a = cur[t - o];
        __syncthreads();
        if (t < 128) cur[t] += a;
        __syncthreads();
    }
    if (t < 128) cur[t] -= buf[t];     // exclusive prefix per degree bin
    __syncthreads();
    if (aliveT) {
        const int r = atomicAdd(&cur[myb], 1);
        nodeperm[(b << BSHIFT) + r] = nodeT;
    }
}

// ============================== AGNN: 4 lanes per node, degree-sorted =======
// node = nodeperm[gid]: the 16 nodes in a wave have near-equal degree, so the
// wave-uniform trip count ~ own degree (no masked-iteration waste). Lane group
// ls=0..3 splits the edge list 4-ways (4 gather chains/node, 6 waves/SIMD).
// Epilogue: 2-round shfl reduce per node. LAST=1 fuses lin2+log_softmax.
template <int LAST>
__global__ __launch_bounds__(256) void k_agnn(const int* __restrict__ nodeperm,
                                              const int* __restrict__ row_start,
                                              const unsigned short* __restrict__ row_cnt,
                                              const int* __restrict__ csr_src,
                                              const unsigned short* __restrict__ xnb,
                                              const float* __restrict__ normv,
                                              const float* __restrict__ betap,
                                              const float* __restrict__ w2,
                                              const float* __restrict__ b2,
                                              float* __restrict__ out,
                                              unsigned short* __restrict__ outb,
                                              float* __restrict__ out_norm) {
    __shared__ float w2s[HID][N_CLASS + 1];   // transposed: w2s[k][j]
    __shared__ float b2s[N_CLASS];

    const int t256 = threadIdx.x;
    const int ls   = t256 & 3;
    const int gid  = blockIdx.x * 64 + (t256 >> 2);
    const bool alive = gid < N_NODES;
    const int node = alive ? nodeperm[gid] : 0;

    if (LAST) {
        for (int i = t256; i < N_CLASS * HID; i += 256)
            w2s[i % HID][i / HID] = w2[i];
        if (t256 < N_CLASS) b2s[t256] = b2[t256];
        __syncthreads();
    }

    const int rs  = alive ? row_start[node] : 0;
    const int cnt = alive ? (int)row_cnt[node] : 0;

    const float beta  = betap ? betap[0] : 1.0f;
    const float shift = fabsf(beta);

    // own (dst) row
    const bf16x8* xd = (const bf16x8*)(xnb + (size_t)node * HID);
    const bf16x8 dlo = xd[0], dhi = xd[1];
    float dd[16];
#pragma unroll
    for (int i = 0; i < 8; i++) {
        dd[i]     = bf2f((unsigned short)dlo[i]);
        dd[i + 8] = bf2f((unsigned short)dhi[i]);
    }

    // wave-uniform trip count (degree-sorted -> minimal slack)
    int mcnt = (cnt + 3) >> 2;
#pragma unroll
    for (int m = 1; m < 64; m <<= 1) mcnt = max(mcnt, __shfl_xor(mcnt, m));

    float acc[16];
#pragma unroll
    for (int i = 0; i < 16; i++) acc[i] = 0.f;
    float swl = 0.f;

    // pipeline: prefetch this lane's edge 0
    bool ok = (ls < cnt);
    int sidx = ok ? csr_src[rs + ls] : 0;
    const bf16x8* xs0 = (const bf16x8*)(xnb + (size_t)sidx * HID);
    bf16x8 slo = xs0[0], shi = xs0[1];
    float nj = normv[sidx];

    for (int t = 0; t < mcnt; ++t) {
        const int e2 = 4 * (t + 1) + ls;
        const bool ok2 = (e2 < cnt);
        const int sidx2 = ok2 ? csr_src[rs + e2] : 0;
        const bf16x8* xs2 = (const bf16x8*)(xnb + (size_t)sidx2 * HID);
        const bf16x8 slo2 = xs2[0], shi2 = xs2[1];
        const float nj2 = normv[sidx2];

        float sr[16];
#pragma unroll
        for (int i = 0; i < 8; i++) {
            sr[i]     = bf2f((unsigned short)slo[i]);
            sr[i + 8] = bf2f((unsigned short)shi[i]);
        }
        float p0 = 0.f, p1 = 0.f, p2 = 0.f, p3 = 0.f;
#pragma unroll
        for (int i = 0; i < 4; i++) {
            p0 += sr[i]      * dd[i];
            p1 += sr[i + 4]  * dd[i + 4];
            p2 += sr[i + 8]  * dd[i + 8];
            p3 += sr[i + 12] * dd[i + 12];
        }
        const float dot = (p0 + p1) + (p2 + p3);
        const float w = ok ? __expf(beta * dot - shift) : 0.f;
        swl += w;
        const float wn = w * nj;
#pragma unroll
        for (int i = 0; i < 16; i++) acc[i] += wn * sr[i];

        slo = slo2; shi = shi2; nj = nj2; ok = ok2;
    }

    // reduce acc[16] + sw across the 4-lane group (epilogue-only)
#pragma unroll
    for (int m = 1; m < 4; m <<= 1) {
#pragma unroll
        for (int i = 0; i < 16; i++) acc[i] += __shfl_xor(acc[i], m);
        swl += __shfl_xor(swl, m);
    }

    const float inv = 1.f / fmaxf(swl, 1e-16f);
    float v[16];
#pragma unroll
    for (int i = 0; i < 16; i++) v[i] = acc[i] * inv;

    if (!LAST) {
        float ss = 0.f;
#pragma unroll
        for (int i = 0; i < 16; i++) ss += v[i] * v[i];
        const float nrm = sqrtf(ss);
        const float rn  = 1.f / fmaxf(nrm, 1e-12f);
        if (alive && ls == 0) {
            bf16x8 o0, o1;
#pragma unroll
            for (int i = 0; i < 8; i++) {
                o0[i] = (short)f2bf_rtn(v[i] * rn);
                o1[i] = (short)f2bf_rtn(v[i + 8] * rn);
            }
            bf16x8* orow = (bf16x8*)(outb + (size_t)node * HID);
            orow[0] = o0; orow[1] = o1;
            out_norm[node] = nrm;
        }
    } else {
        // fused lin2 + log_softmax; lane ls computes classes [10ls, 10ls+10)
        const int j0 = ls * 10;
        float lg[10];
#pragma unroll
        for (int j = 0; j < 10; j++) lg[j] = b2s[j0 + j];
#pragma unroll
        for (int k = 0; k < HID; k++) {
            const float vk = v[k];
#pragma unroll
            for (int j = 0; j < 10; j++) lg[j] += vk * w2s[k][j0 + j];
        }
        float m = -3.0e38f;
#pragma unroll
        for (int j = 0; j < 10; j++) m = fmaxf(m, lg[j]);
        m = fmaxf(m, __shfl_xor(m, 1)); m = fmaxf(m, __shfl_xor(m, 2));
        float s = 0.f;
#pragma unroll
        for (int j = 0; j < 10; j++) s += __expf(lg[j] - m);
        s += __shfl_xor(s, 1); s += __shfl_xor(s, 2);
        const float lse = m + __logf(s);
        if (alive) {
            float* orow = out + (size_t)node * N_CLASS + j0;
#pragma unroll
            for (int j = 0; j < 10; j++) orow[j] = lg[j] - lse;
        }
    }
}

// ============================== Launch ======================================
extern "C" void kernel_launch(void* const* d_in, const int* in_sizes, int n_in,
                              void* d_out, int out_size, void* d_ws, size_t ws_size,
                              hipStream_t stream) {
    const float* x     = (const float*)d_in[0];
    const int*   ei    = (const int*)  d_in[1];   // [2][E]: row0=src, row1=dst
    const float* w1    = (const float*)d_in[2];
    const float* b1    = (const float*)d_in[3];
    const float* beta2 = (const float*)d_in[4];
    const float* w2    = (const float*)d_in[5];
    const float* b2    = (const float*)d_in[6];
    float* out = (float*)d_out;

    const int* srcp = ei;
    const int* dstp = ei + N_EDGES;

    // workspace layout (~23 MB)
    unsigned short* xnb1 = (unsigned short*)d_ws;        // [N,16] bf16 unit rows
    unsigned short* xnb2 = xnb1 + (size_t)N_NODES * HID; // [N,16] bf16
    float* norm1 = (float*)(xnb2 + (size_t)N_NODES * HID); // [N]
    float* norm2 = norm1 + N_NODES;                      // [N]
    int* row_start = (int*)(norm2 + N_NODES);            // [N]
    unsigned short* row_cnt = (unsigned short*)(row_start + N_NODES); // [N]
    int* nodeperm = (int*)(row_cnt + N_NODES + (N_NODES & 1)); // [N]
    int* cursor = nodeperm + N_NODES;                    // [NB]
    int* binned = cursor + NB + 2;                       // [NB*CAP] padded

    const int agnnGrid = (N_NODES + 63) / 64;          // 1563

    hipMemsetAsync(cursor, 0, NB * sizeof(int), stream);

    // ---- fused CSR-binning + lin1 (independent pipelines, one dispatch) ----
    k_bin_lin1<<<BIN_BLOCKS + LIN1_BLOCKS, 256, 0, stream>>>(
        srcp, dstp, cursor, binned, x, w1, b1, xnb1, norm1);

    k_csr<<<NB, 512, 0, stream>>>(cursor, binned, row_start, row_cnt, nodeperm);

    // ---- AGNN layers (4 lanes/node, degree-sorted waves) ----
    k_agnn<0><<<agnnGrid, 256, 0, stream>>>(nodeperm, row_start, row_cnt, binned,
                                            xnb1, norm1, nullptr, nullptr,
                                            nullptr, nullptr, xnb2, norm2);
    k_agnn<1><<<agnnGrid, 256, 0, stream>>>(nodeperm, row_start, row_cnt, binned,
                                            xnb2, norm2, beta2, w2, b2,
                                            out, nullptr, nullptr);
}

// Round 17
// 170.903 us; speedup vs baseline: 1.2231x; 1.2231x over previous
//
#include <hip/hip_runtime.h>

#define N_NODES 100000
#define N_EDGES 3200000
#define N_FEAT  512
#define HID     16
#define N_CLASS 40

#define BSHIFT  9                      // 512 nodes per bucket
#define BMASK   ((1 << BSHIFT) - 1)
#define NB      196                    // ceil(100000 / 512)
#define CAP     18432                  // padded bucket region (mean 16384, +16 sigma)
#define EPB     4096                   // edges per binning block
#define EC_CAP  3072                   // staged edges per 64-node block (+22 sigma)

#define BIN_BLOCKS  ((N_EDGES + EPB - 1) / EPB)   // 782
#define NT_TILES    (N_NODES / 16)                // 6250 lin1 tiles
#define LIN1_BLOCKS ((NT_TILES + 3) / 4)          // 1563

typedef __attribute__((ext_vector_type(8))) short bf16x8;
typedef __attribute__((ext_vector_type(4))) float f32x4;

__device__ inline short2 split_bf(float v) {
    const unsigned u = __float_as_uint(v);
    const short hi = (short)(u >> 16);
    const float hf = __uint_as_float(u & 0xFFFF0000u);
    const short lo = (short)(__float_as_uint(v - hf) >> 16);
    return make_short2(hi, lo);
}
__device__ inline unsigned short f2bf_rtn(float v) {
    unsigned u = __float_as_uint(v);
    u += 0x7FFFu + ((u >> 16) & 1u);
    return (unsigned short)(u >> 16);
}
__device__ inline float bf2f(unsigned short u) {
    return __uint_as_float(((unsigned)u) << 16);
}

// ================= Fused: CSR binning (blocks 0..781) + lin1 (rest) =========
struct BinSmem {
    int hist[NB]; int lofs[NB]; int base[NB]; int rk[NB];
    int buf[256]; int stage[EPB]; unsigned short sbkt[EPB];
};
struct Lin1Smem { short bfH[16 * 64 * 8]; short bfL[16 * 64 * 8]; };

__device__ void bin_body(char* smemraw,
                         const int* __restrict__ src,
                         const int* __restrict__ dst,
                         int* __restrict__ cursor,
                         int* __restrict__ binned) {
    BinSmem& sm = *(BinSmem*)smemraw;
    const int t = threadIdx.x;
    for (int i = t; i < NB; i += 256) { sm.hist[i] = 0; sm.rk[i] = 0; }
    __syncthreads();

    const int e0 = blockIdx.x * EPB;
    int bk[EPB / 256];
    int vv[EPB / 256];
#pragma unroll
    for (int k = 0; k < EPB / 256; k++) {
        const int e = e0 + k * 256 + t;
        if (e < N_EDGES) {
            const int d = dst[e], s = src[e];
            bk[k] = d >> BSHIFT;
            vv[k] = (s << BSHIFT) | (d & BMASK);
            atomicAdd(&sm.hist[bk[k]], 1);
        } else bk[k] = -1;
    }
    __syncthreads();

    {
        const int v = (t < NB) ? sm.hist[t] : 0;
        sm.buf[t] = v; __syncthreads();
        for (int o = 1; o < 256; o <<= 1) {
            const int a = (t >= o) ? sm.buf[t - o] : 0;
            __syncthreads();
            sm.buf[t] += a;
            __syncthreads();
        }
        if (t < NB) sm.lofs[t] = sm.buf[t] - v;
    }
    if (t < NB && sm.hist[t] > 0)
        sm.base[t] = t * CAP + atomicAdd(&cursor[t], sm.hist[t]);

#pragma unroll
    for (int k = 0; k < EPB / 256; k++) {
        if (bk[k] >= 0) {
            const int r = atomicAdd(&sm.rk[bk[k]], 1);
            const int slot = sm.lofs[bk[k]] + r;
            sm.stage[slot] = vv[k];
            sm.sbkt[slot] = (unsigned short)bk[k];
        }
    }
    __syncthreads();

    const int nloc = min(EPB, N_EDGES - e0);
    for (int s2 = t; s2 < nloc; s2 += 256) {
        const int b = sm.sbkt[s2];
        binned[sm.base[b] + (s2 - sm.lofs[b])] = sm.stage[s2];
    }
}

__device__ void lin1_body(char* smemraw, int lblk,
                          const float* __restrict__ x,
                          const float* __restrict__ w1,
                          const float* __restrict__ b1,
                          unsigned short* __restrict__ xnb,
                          float* __restrict__ normv) {
    Lin1Smem& sm = *(Lin1Smem*)smemraw;
    const int t = threadIdx.x;
    for (int f = t; f < 16 * 64; f += 256) {
        const int kt  = f >> 6;
        const int ln  = f & 63;
        const int col = ln & 15;
        const int k0  = kt * 32 + (ln >> 4) * 8;
        const float4 v0 = *(const float4*)(w1 + col * N_FEAT + k0);
        const float4 v1 = *(const float4*)(w1 + col * N_FEAT + k0 + 4);
        bf16x8 hh, ll;
        short2 r;
        r = split_bf(v0.x); hh[0] = r.x; ll[0] = r.y;
        r = split_bf(v0.y); hh[1] = r.x; ll[1] = r.y;
        r = split_bf(v0.z); hh[2] = r.x; ll[2] = r.y;
        r = split_bf(v0.w); hh[3] = r.x; ll[3] = r.y;
        r = split_bf(v1.x); hh[4] = r.x; ll[4] = r.y;
        r = split_bf(v1.y); hh[5] = r.x; ll[5] = r.y;
        r = split_bf(v1.z); hh[6] = r.x; ll[6] = r.y;
        r = split_bf(v1.w); hh[7] = r.x; ll[7] = r.y;
        ((bf16x8*)sm.bfH)[f] = hh;
        ((bf16x8*)sm.bfL)[f] = ll;
    }
    __syncthreads();

    const int wv   = t >> 6;
    const int l    = t & 63;
    const int tile = lblk * 4 + wv;
    if (tile >= NT_TILES) return;

    const int r0 = tile * 16;
    const float* xp = x + (size_t)(r0 + (l & 15)) * N_FEAT + ((l >> 4) * 8);

    f32x4 acc = {0.f, 0.f, 0.f, 0.f};
    float4 c0 = *(const float4*)(xp);
    float4 c1 = *(const float4*)(xp + 4);
#pragma unroll
    for (int kt = 0; kt < 16; ++kt) {
        float4 n0, n1;
        if (kt < 15) {
            n0 = *(const float4*)(xp + (kt + 1) * 32);
            n1 = *(const float4*)(xp + (kt + 1) * 32 + 4);
        }
        bf16x8 ah, al;
        short2 r;
        r = split_bf(c0.x); ah[0] = r.x; al[0] = r.y;
        r = split_bf(c0.y); ah[1] = r.x; al[1] = r.y;
        r = split_bf(c0.z); ah[2] = r.x; al[2] = r.y;
        r = split_bf(c0.w); ah[3] = r.x; al[3] = r.y;
        r = split_bf(c1.x); ah[4] = r.x; al[4] = r.y;
        r = split_bf(c1.y); ah[5] = r.x; al[5] = r.y;
        r = split_bf(c1.z); ah[6] = r.x; al[6] = r.y;
        r = split_bf(c1.w); ah[7] = r.x; al[7] = r.y;
        const bf16x8 bh = ((const bf16x8*)sm.bfH)[kt * 64 + l];
        const bf16x8 bl = ((const bf16x8*)sm.bfL)[kt * 64 + l];
        acc = __builtin_amdgcn_mfma_f32_16x16x32_bf16(ah, bh, acc, 0, 0, 0);
        acc = __builtin_amdgcn_mfma_f32_16x16x32_bf16(al, bh, acc, 0, 0, 0);
        acc = __builtin_amdgcn_mfma_f32_16x16x32_bf16(ah, bl, acc, 0, 0, 0);
        c0 = n0; c1 = n1;
    }

    const float bias = b1[l & 15];
#pragma unroll
    for (int r = 0; r < 4; ++r) {
        const float v = fmaxf(acc[r] + bias, 0.f);
        float ss = v * v;
        ss += __shfl_xor(ss, 1); ss += __shfl_xor(ss, 2);
        ss += __shfl_xor(ss, 4); ss += __shfl_xor(ss, 8);
        const float nrm = sqrtf(ss);
        const float rn  = 1.f / fmaxf(nrm, 1e-12f);
        const int row = r0 + (l >> 4) * 4 + r;
        xnb[(size_t)row * HID + (l & 15)] = f2bf_rtn(v * rn);
        if ((l & 15) == 0) normv[row] = nrm;
    }
}

__global__ __launch_bounds__(256) void k_bin_lin1(const int* __restrict__ src,
                                                  const int* __restrict__ dst,
                                                  int* __restrict__ cursor,
                                                  int* __restrict__ binned,
                                                  const float* __restrict__ x,
                                                  const float* __restrict__ w1,
                                                  const float* __restrict__ b1,
                                                  unsigned short* __restrict__ xnb,
                                                  float* __restrict__ normv) {
    __shared__ __align__(16) char smem[sizeof(Lin1Smem) > sizeof(BinSmem)
                                       ? sizeof(Lin1Smem) : sizeof(BinSmem)];
    if (blockIdx.x < BIN_BLOCKS)
        bin_body(smem, src, dst, cursor, binned);
    else
        lin1_body(smem, blockIdx.x - BIN_BLOCKS, x, w1, b1, xnb, normv);
}

// ============================== k_csr =======================================
__global__ __launch_bounds__(512) void k_csr(const int* __restrict__ cursor,
                                             int* __restrict__ binned,
                                             int* __restrict__ row_start,
                                             unsigned short* __restrict__ row_cnt) {
    __shared__ int cnts[512];
    __shared__ int cur[512];
    __shared__ int buf[512];
    __shared__ int lcsr[CAP];

    const int t = threadIdx.x;
    const int b = blockIdx.x;
    const int s0 = b * CAP;
    const int n = cursor[b];

    cnts[t] = 0;
    __syncthreads();
    for (int i = t; i < n; i += 512)
        atomicAdd(&cnts[binned[s0 + i] & BMASK], 1);
    __syncthreads();

    {
        const int v = cnts[t];
        buf[t] = v; __syncthreads();
        for (int o = 1; o < 512; o <<= 1) {
            const int a = (t >= o) ? buf[t - o] : 0;
            __syncthreads();
            buf[t] += a;
            __syncthreads();
        }
        cur[t] = buf[t] - v;
        const int node = (b << BSHIFT) + t;
        if (node < N_NODES) {
            row_start[node] = s0 + cur[t];
            row_cnt[node]   = (unsigned short)v;
        }
    }
    __syncthreads();

    for (int i = t; i < n; i += 512) {
        const int v = binned[s0 + i];
        const int p = atomicAdd(&cur[v & BMASK], 1);
        lcsr[p] = v >> BSHIFT;
    }
    __syncthreads();

    for (int i = t; i < n; i += 512) binned[s0 + i] = lcsr[i];
}

// ============================== AGNN: 4 lanes per node, depth-2 pipeline ====
// 64 nodes/block (never straddles a bucket). Lane group ls=0..3 splits each
// node's edge list 4-ways. Depth-2 register rotation (A<-B<-C, named vars,
// compile-time indices): TWO independent row-gathers in flight per lane.
// Epilogue: 2-round shfl reduce per node. LAST=1 fuses lin2+log_softmax.
template <int LAST>
__global__ __launch_bounds__(256) void k_agnn(const int* __restrict__ row_start,
                                              const unsigned short* __restrict__ row_cnt,
                                              const int* __restrict__ csr_src,
                                              const unsigned short* __restrict__ xnb,
                                              const float* __restrict__ normv,
                                              const float* __restrict__ betap,
                                              const float* __restrict__ w2,
                                              const float* __restrict__ b2,
                                              float* __restrict__ out,
                                              unsigned short* __restrict__ outb,
                                              float* __restrict__ out_norm) {
    __shared__ int ldsCsr[EC_CAP];
    __shared__ float w2s[HID][N_CLASS + 1];   // transposed: w2s[k][j]
    __shared__ float b2s[N_CLASS];
    __shared__ int sRs0, sNE;

    const int t256 = threadIdx.x;
    const int ls   = t256 & 3;
    const int node = blockIdx.x * 64 + (t256 >> 2);
    const bool alive = node < N_NODES;

    if (LAST) {
        for (int i = t256; i < N_CLASS * HID; i += 256)
            w2s[i % HID][i / HID] = w2[i];
        if (t256 < N_CLASS) b2s[t256] = b2[t256];
    }

    const int rs  = alive ? row_start[node] : 0;
    const int cnt = alive ? (int)row_cnt[node] : 0;

    if (t256 == 0) {
        const int base = blockIdx.x * 64;
        const int last = min(base + 64, N_NODES) - 1;
        const int r0 = row_start[base];
        sRs0 = r0;
        sNE  = row_start[last] + (int)row_cnt[last] - r0;
    }
    __syncthreads();
    const int rs0 = sRs0;
    const int nStage = min(sNE, EC_CAP);
    for (int i = t256; i < nStage; i += 256)
        ldsCsr[i] = csr_src[rs0 + i];
    __syncthreads();

    const float beta  = betap ? betap[0] : 1.0f;
    const float shift = fabsf(beta);
    const int off = rs - rs0;

    // own (dst) row
    const int nodeSafe = alive ? node : 0;
    const bf16x8* xd = (const bf16x8*)(xnb + (size_t)nodeSafe * HID);
    const bf16x8 dlo = xd[0], dhi = xd[1];
    float dd[16];
#pragma unroll
    for (int i = 0; i < 8; i++) {
        dd[i]     = bf2f((unsigned short)dlo[i]);
        dd[i + 8] = bf2f((unsigned short)dhi[i]);
    }

    // wave-uniform trip count: max ceil(cnt/4) over wave
    int mcnt = (cnt + 3) >> 2;
#pragma unroll
    for (int m = 1; m < 64; m <<= 1) mcnt = max(mcnt, __shfl_xor(mcnt, m));

    float acc[16];
#pragma unroll
    for (int i = 0; i < 16; i++) acc[i] = 0.f;
    float swl = 0.f;

    // depth-2 pipeline prologue: A = edge ls, B = edge 4+ls
    bool okA = (ls < cnt);
    int sA = 0;
    if (okA) { const int p = off + ls; sA = (p < nStage) ? ldsCsr[p] : csr_src[rs + ls]; }
    const bf16x8* xA = (const bf16x8*)(xnb + (size_t)sA * HID);
    bf16x8 aLo = xA[0], aHi = xA[1];
    float njA = normv[sA];

    bool okB = (4 + ls < cnt);
    int sB = 0;
    if (okB) { const int p = off + 4 + ls; sB = (p < nStage) ? ldsCsr[p] : csr_src[rs + 4 + ls]; }
    const bf16x8* xB = (const bf16x8*)(xnb + (size_t)sB * HID);
    bf16x8 bLo = xB[0], bHi = xB[1];
    float njB = normv[sB];

    for (int t = 0; t < mcnt; ++t) {
        // prefetch edge 4(t+2)+ls -> C
        const int e2 = 4 * (t + 2) + ls;
        const bool okC = (e2 < cnt);
        int sC = 0;
        if (okC) { const int p = off + e2; sC = (p < nStage) ? ldsCsr[p] : csr_src[rs + e2]; }
        const bf16x8* xC = (const bf16x8*)(xnb + (size_t)sC * HID);
        const bf16x8 cLo = xC[0], cHi = xC[1];
        const float njC = normv[sC];

        // compute A
        float sr[16];
#pragma unroll
        for (int i = 0; i < 8; i++) {
            sr[i]     = bf2f((unsigned short)aLo[i]);
            sr[i + 8] = bf2f((unsigned short)aHi[i]);
        }
        float p0 = 0.f, p1 = 0.f, p2 = 0.f, p3 = 0.f;
#pragma unroll
        for (int i = 0; i < 4; i++) {
            p0 += sr[i]      * dd[i];
            p1 += sr[i + 4]  * dd[i + 4];
            p2 += sr[i + 8]  * dd[i + 8];
            p3 += sr[i + 12] * dd[i + 12];
        }
        const float dot = (p0 + p1) + (p2 + p3);
        const float w = okA ? __expf(beta * dot - shift) : 0.f;
        swl += w;
        const float wn = w * njA;
#pragma unroll
        for (int i = 0; i < 16; i++) acc[i] += wn * sr[i];

        // rotate A <- B <- C (named regs, compile-time)
        okA = okB; aLo = bLo; aHi = bHi; njA = njB;
        okB = okC; bLo = cLo; bHi = cHi; njB = njC;
    }

    // reduce acc[16] + sw across the 4-lane group (epilogue-only)
#pragma unroll
    for (int m = 1; m < 4; m <<= 1) {
#pragma unroll
        for (int i = 0; i < 16; i++) acc[i] += __shfl_xor(acc[i], m);
        swl += __shfl_xor(swl, m);
    }

    const float inv = 1.f / fmaxf(swl, 1e-16f);
    float v[16];
#pragma unroll
    for (int i = 0; i < 16; i++) v[i] = acc[i] * inv;

    if (!LAST) {
        float ss = 0.f;
#pragma unroll
        for (int i = 0; i < 16; i++) ss += v[i] * v[i];
        const float nrm = sqrtf(ss);
        const float rn  = 1.f / fmaxf(nrm, 1e-12f);
        if (alive && ls == 0) {
            bf16x8 o0, o1;
#pragma unroll
            for (int i = 0; i < 8; i++) {
                o0[i] = (short)f2bf_rtn(v[i] * rn);
                o1[i] = (short)f2bf_rtn(v[i + 8] * rn);
            }
            bf16x8* orow = (bf16x8*)(outb + (size_t)node * HID);
            orow[0] = o0; orow[1] = o1;
            out_norm[node] = nrm;
        }
    } else {
        // fused lin2 + log_softmax; lane ls computes classes [10ls, 10ls+10)
        const int j0 = ls * 10;
        float lg[10];
#pragma unroll
        for (int j = 0; j < 10; j++) lg[j] = b2s[j0 + j];
#pragma unroll
        for (int k = 0; k < HID; k++) {
            const float vk = v[k];
#pragma unroll
            for (int j = 0; j < 10; j++) lg[j] += vk * w2s[k][j0 + j];
        }
        float m = -3.0e38f;
#pragma unroll
        for (int j = 0; j < 10; j++) m = fmaxf(m, lg[j]);
        m = fmaxf(m, __shfl_xor(m, 1)); m = fmaxf(m, __shfl_xor(m, 2));
        float s = 0.f;
#pragma unroll
        for (int j = 0; j < 10; j++) s += __expf(lg[j] - m);
        s += __shfl_xor(s, 1); s += __shfl_xor(s, 2);
        const float lse = m + __logf(s);
        if (alive) {
            float* orow = out + (size_t)node * N_CLASS + j0;
#pragma unroll
            for (int j = 0; j < 10; j++) orow[j] = lg[j] - lse;
        }
    }
}

// ============================== Launch ======================================
extern "C" void kernel_launch(void* const* d_in, const int* in_sizes, int n_in,
                              void* d_out, int out_size, void* d_ws, size_t ws_size,
                              hipStream_t stream) {
    const float* x     = (const float*)d_in[0];
    const int*   ei    = (const int*)  d_in[1];   // [2][E]: row0=src, row1=dst
    const float* w1    = (const float*)d_in[2];
    const float* b1    = (const float*)d_in[3];
    const float* beta2 = (const float*)d_in[4];
    const float* w2    = (const float*)d_in[5];
    const float* b2    = (const float*)d_in[6];
    float* out = (float*)d_out;

    const int* srcp = ei;
    const int* dstp = ei + N_EDGES;

    // workspace layout (~22 MB)
    unsigned short* xnb1 = (unsigned short*)d_ws;        // [N,16] bf16 unit rows
    unsigned short* xnb2 = xnb1 + (size_t)N_NODES * HID; // [N,16] bf16
    float* norm1 = (float*)(xnb2 + (size_t)N_NODES * HID); // [N]
    float* norm2 = norm1 + N_NODES;                      // [N]
    int* row_start = (int*)(norm2 + N_NODES);            // [N]
    unsigned short* row_cnt = (unsigned short*)(row_start + N_NODES); // [N]
    int* cursor = (int*)(row_cnt + N_NODES + (N_NODES & 1)); // [NB]
    int* binned = cursor + NB + 2;                       // [NB*CAP] padded

    const int agnnGrid = (N_NODES + 63) / 64;          // 1563

    hipMemsetAsync(cursor, 0, NB * sizeof(int), stream);

    // ---- fused CSR-binning + lin1 (independent pipelines, one dispatch) ----
    k_bin_lin1<<<BIN_BLOCKS + LIN1_BLOCKS, 256, 0, stream>>>(
        srcp, dstp, cursor, binned, x, w1, b1, xnb1, norm1);

    k_csr<<<NB, 512, 0, stream>>>(cursor, binned, row_start, row_cnt);

    // ---- AGNN layers (4 lanes/node, depth-2 pipeline) ----
    k_agnn<0><<<agnnGrid, 256, 0, stream>>>(row_start, row_cnt, binned, xnb1,
                                            norm1, nullptr, nullptr, nullptr,
                                            nullptr, xnb2, norm2);
    k_agnn<1><<<agnnGrid, 256, 0, stream>>>(row_start, row_cnt, binned, xnb2,
                                            norm2, beta2, w2, b2,
                                            out, nullptr, nullptr);
}

// Round 18
// 166.019 us; speedup vs baseline: 1.2591x; 1.0294x over previous
//
#include <hip/hip_runtime.h>

#define N_NODES 100000
#define N_EDGES 3200000
#define N_FEAT  512
#define HID     16
#define N_CLASS 40

#define BSHIFT  9                      // 512 nodes per bucket
#define BMASK   ((1 << BSHIFT) - 1)
#define NB      196                    // ceil(100000 / 512)
#define CAP     18432                  // padded bucket region (mean 16384, +16 sigma)
#define EPB     4096                   // edges per binning block
#define EC_CAP  3072                   // staged edges per 64-node block (+22 sigma)

#define BIN_BLOCKS  ((N_EDGES + EPB - 1) / EPB)   // 782
#define NT_TILES    (N_NODES / 16)                // 6250 lin1 tiles
#define LIN1_BLOCKS ((NT_TILES + 3) / 4)          // 1563

typedef __attribute__((ext_vector_type(8))) short bf16x8;
typedef __attribute__((ext_vector_type(4))) float f32x4;

__device__ inline short2 split_bf(float v) {
    const unsigned u = __float_as_uint(v);
    const short hi = (short)(u >> 16);
    const float hf = __uint_as_float(u & 0xFFFF0000u);
    const short lo = (short)(__float_as_uint(v - hf) >> 16);
    return make_short2(hi, lo);
}
__device__ inline unsigned short f2bf_rtn(float v) {
    unsigned u = __float_as_uint(v);
    u += 0x7FFFu + ((u >> 16) & 1u);
    return (unsigned short)(u >> 16);
}
__device__ inline float bf2f(unsigned short u) {
    return __uint_as_float(((unsigned)u) << 16);
}

// ================= Fused: CSR binning (blocks 0..781) + lin1 (rest) =========
struct BinSmem {
    int hist[NB]; int lofs[NB]; int base[NB]; int rk[NB];
    int buf[256]; int stage[EPB]; unsigned short sbkt[EPB];
};
struct Lin1Smem { short bfH[16 * 64 * 8]; short bfL[16 * 64 * 8]; };

__device__ void bin_body(char* smemraw,
                         const int* __restrict__ src,
                         const int* __restrict__ dst,
                         int* __restrict__ cursor,
                         int* __restrict__ binned) {
    BinSmem& sm = *(BinSmem*)smemraw;
    const int t = threadIdx.x;
    for (int i = t; i < NB; i += 256) { sm.hist[i] = 0; sm.rk[i] = 0; }
    __syncthreads();

    const int e0 = blockIdx.x * EPB;
    int bk[EPB / 256];
    int vv[EPB / 256];
#pragma unroll
    for (int k = 0; k < EPB / 256; k++) {
        const int e = e0 + k * 256 + t;
        if (e < N_EDGES) {
            const int d = dst[e], s = src[e];
            bk[k] = d >> BSHIFT;
            vv[k] = (s << BSHIFT) | (d & BMASK);
            atomicAdd(&sm.hist[bk[k]], 1);
        } else bk[k] = -1;
    }
    __syncthreads();

    {
        const int v = (t < NB) ? sm.hist[t] : 0;
        sm.buf[t] = v; __syncthreads();
        for (int o = 1; o < 256; o <<= 1) {
            const int a = (t >= o) ? sm.buf[t - o] : 0;
            __syncthreads();
            sm.buf[t] += a;
            __syncthreads();
        }
        if (t < NB) sm.lofs[t] = sm.buf[t] - v;
    }
    if (t < NB && sm.hist[t] > 0)
        sm.base[t] = t * CAP + atomicAdd(&cursor[t], sm.hist[t]);

#pragma unroll
    for (int k = 0; k < EPB / 256; k++) {
        if (bk[k] >= 0) {
            const int r = atomicAdd(&sm.rk[bk[k]], 1);
            const int slot = sm.lofs[bk[k]] + r;
            sm.stage[slot] = vv[k];
            sm.sbkt[slot] = (unsigned short)bk[k];
        }
    }
    __syncthreads();

    const int nloc = min(EPB, N_EDGES - e0);
    for (int s2 = t; s2 < nloc; s2 += 256) {
        const int b = sm.sbkt[s2];
        binned[sm.base[b] + (s2 - sm.lofs[b])] = sm.stage[s2];
    }
}

__device__ void lin1_body(char* smemraw, int lblk,
                          const float* __restrict__ x,
                          const float* __restrict__ w1,
                          const float* __restrict__ b1,
                          unsigned short* __restrict__ xnb,
                          float* __restrict__ normv) {
    Lin1Smem& sm = *(Lin1Smem*)smemraw;
    const int t = threadIdx.x;
    for (int f = t; f < 16 * 64; f += 256) {
        const int kt  = f >> 6;
        const int ln  = f & 63;
        const int col = ln & 15;
        const int k0  = kt * 32 + (ln >> 4) * 8;
        const float4 v0 = *(const float4*)(w1 + col * N_FEAT + k0);
        const float4 v1 = *(const float4*)(w1 + col * N_FEAT + k0 + 4);
        bf16x8 hh, ll;
        short2 r;
        r = split_bf(v0.x); hh[0] = r.x; ll[0] = r.y;
        r = split_bf(v0.y); hh[1] = r.x; ll[1] = r.y;
        r = split_bf(v0.z); hh[2] = r.x; ll[2] = r.y;
        r = split_bf(v0.w); hh[3] = r.x; ll[3] = r.y;
        r = split_bf(v1.x); hh[4] = r.x; ll[4] = r.y;
        r = split_bf(v1.y); hh[5] = r.x; ll[5] = r.y;
        r = split_bf(v1.z); hh[6] = r.x; ll[6] = r.y;
        r = split_bf(v1.w); hh[7] = r.x; ll[7] = r.y;
        ((bf16x8*)sm.bfH)[f] = hh;
        ((bf16x8*)sm.bfL)[f] = ll;
    }
    __syncthreads();

    const int wv   = t >> 6;
    const int l    = t & 63;
    const int tile = lblk * 4 + wv;
    if (tile >= NT_TILES) return;

    const int r0 = tile * 16;
    const float* xp = x + (size_t)(r0 + (l & 15)) * N_FEAT + ((l >> 4) * 8);

    f32x4 acc = {0.f, 0.f, 0.f, 0.f};
    float4 c0 = *(const float4*)(xp);
    float4 c1 = *(const float4*)(xp + 4);
#pragma unroll
    for (int kt = 0; kt < 16; ++kt) {
        float4 n0, n1;
        if (kt < 15) {
            n0 = *(const float4*)(xp + (kt + 1) * 32);
            n1 = *(const float4*)(xp + (kt + 1) * 32 + 4);
        }
        bf16x8 ah, al;
        short2 r;
        r = split_bf(c0.x); ah[0] = r.x; al[0] = r.y;
        r = split_bf(c0.y); ah[1] = r.x; al[1] = r.y;
        r = split_bf(c0.z); ah[2] = r.x; al[2] = r.y;
        r = split_bf(c0.w); ah[3] = r.x; al[3] = r.y;
        r = split_bf(c1.x); ah[4] = r.x; al[4] = r.y;
        r = split_bf(c1.y); ah[5] = r.x; al[5] = r.y;
        r = split_bf(c1.z); ah[6] = r.x; al[6] = r.y;
        r = split_bf(c1.w); ah[7] = r.x; al[7] = r.y;
        const bf16x8 bh = ((const bf16x8*)sm.bfH)[kt * 64 + l];
        const bf16x8 bl = ((const bf16x8*)sm.bfL)[kt * 64 + l];
        acc = __builtin_amdgcn_mfma_f32_16x16x32_bf16(ah, bh, acc, 0, 0, 0);
        acc = __builtin_amdgcn_mfma_f32_16x16x32_bf16(al, bh, acc, 0, 0, 0);
        acc = __builtin_amdgcn_mfma_f32_16x16x32_bf16(ah, bl, acc, 0, 0, 0);
        c0 = n0; c1 = n1;
    }

    const float bias = b1[l & 15];
#pragma unroll
    for (int r = 0; r < 4; ++r) {
        const float v = fmaxf(acc[r] + bias, 0.f);
        float ss = v * v;
        ss += __shfl_xor(ss, 1); ss += __shfl_xor(ss, 2);
        ss += __shfl_xor(ss, 4); ss += __shfl_xor(ss, 8);
        const float nrm = sqrtf(ss);
        const float rn  = 1.f / fmaxf(nrm, 1e-12f);
        const int row = r0 + (l >> 4) * 4 + r;
        xnb[(size_t)row * HID + (l & 15)] = f2bf_rtn(v * rn);
        if ((l & 15) == 0) normv[row] = nrm;
    }
}

__global__ __launch_bounds__(256) void k_bin_lin1(const int* __restrict__ src,
                                                  const int* __restrict__ dst,
                                                  int* __restrict__ cursor,
                                                  int* __restrict__ binned,
                                                  const float* __restrict__ x,
                                                  const float* __restrict__ w1,
                                                  const float* __restrict__ b1,
                                                  unsigned short* __restrict__ xnb,
                                                  float* __restrict__ normv) {
    __shared__ __align__(16) char smem[sizeof(Lin1Smem) > sizeof(BinSmem)
                                       ? sizeof(Lin1Smem) : sizeof(BinSmem)];
    if (blockIdx.x < BIN_BLOCKS)
        bin_body(smem, src, dst, cursor, binned);
    else
        lin1_body(smem, blockIdx.x - BIN_BLOCKS, x, w1, b1, xnb, normv);
}

// ============================== k_csr =======================================
__global__ __launch_bounds__(512) void k_csr(const int* __restrict__ cursor,
                                             int* __restrict__ binned,
                                             int* __restrict__ row_start,
                                             unsigned short* __restrict__ row_cnt) {
    __shared__ int cnts[512];
    __shared__ int cur[512];
    __shared__ int buf[512];
    __shared__ int lcsr[CAP];

    const int t = threadIdx.x;
    const int b = blockIdx.x;
    const int s0 = b * CAP;
    const int n = cursor[b];

    cnts[t] = 0;
    __syncthreads();
    for (int i = t; i < n; i += 512)
        atomicAdd(&cnts[binned[s0 + i] & BMASK], 1);
    __syncthreads();

    {
        const int v = cnts[t];
        buf[t] = v; __syncthreads();
        for (int o = 1; o < 512; o <<= 1) {
            const int a = (t >= o) ? buf[t - o] : 0;
            __syncthreads();
            buf[t] += a;
            __syncthreads();
        }
        cur[t] = buf[t] - v;
        const int node = (b << BSHIFT) + t;
        if (node < N_NODES) {
            row_start[node] = s0 + cur[t];
            row_cnt[node]   = (unsigned short)v;
        }
    }
    __syncthreads();

    for (int i = t; i < n; i += 512) {
        const int v = binned[s0 + i];
        const int p = atomicAdd(&cur[v & BMASK], 1);
        lcsr[p] = v >> BSHIFT;
    }
    __syncthreads();

    for (int i = t; i < n; i += 512) binned[s0 + i] = lcsr[i];
}

// ============================== AGNN: 4 lanes per node ======================
// 64 nodes/block (never straddles a 512-node bucket). Lane group ls=0..3 splits
// each node's edge list 4-ways: 4 independent gather chains per node + 4x the
// wave count (6 waves/SIMD) -> latency hidden. Epilogue: 2-round shfl_xor
// reduce of acc[16]/sw over the 4-lane group (once per node). LAST=1 fuses
// lin2+log_softmax, each lane computing 10 of 40 classes.
template <int LAST>
__global__ __launch_bounds__(256) void k_agnn(const int* __restrict__ row_start,
                                              const unsigned short* __restrict__ row_cnt,
                                              const int* __restrict__ csr_src,
                                              const unsigned short* __restrict__ xnb,
                                              const float* __restrict__ normv,
                                              const float* __restrict__ betap,
                                              const float* __restrict__ w2,
                                              const float* __restrict__ b2,
                                              float* __restrict__ out,
                                              unsigned short* __restrict__ outb,
                                              float* __restrict__ out_norm) {
    __shared__ int ldsCsr[EC_CAP];
    __shared__ float w2s[HID][N_CLASS + 1];   // transposed: w2s[k][j]
    __shared__ float b2s[N_CLASS];
    __shared__ int sRs0, sNE;

    const int t256 = threadIdx.x;
    const int ls   = t256 & 3;
    const int node = blockIdx.x * 64 + (t256 >> 2);
    const bool alive = node < N_NODES;

    if (LAST) {
        for (int i = t256; i < N_CLASS * HID; i += 256)
            w2s[i % HID][i / HID] = w2[i];
        if (t256 < N_CLASS) b2s[t256] = b2[t256];
    }

    const int rs  = alive ? row_start[node] : 0;
    const int cnt = alive ? (int)row_cnt[node] : 0;

    if (t256 == 0) {
        const int base = blockIdx.x * 64;
        const int last = min(base + 64, N_NODES) - 1;
        const int r0 = row_start[base];
        sRs0 = r0;
        sNE  = row_start[last] + (int)row_cnt[last] - r0;
    }
    __syncthreads();
    const int rs0 = sRs0;
    const int nStage = min(sNE, EC_CAP);
    for (int i = t256; i < nStage; i += 256)
        ldsCsr[i] = csr_src[rs0 + i];
    __syncthreads();

    const float beta  = betap ? betap[0] : 1.0f;
    const float shift = fabsf(beta);
    const int off = rs - rs0;

    // own (dst) row
    const int nodeSafe = alive ? node : 0;
    const bf16x8* xd = (const bf16x8*)(xnb + (size_t)nodeSafe * HID);
    const bf16x8 dlo = xd[0], dhi = xd[1];
    float dd[16];
#pragma unroll
    for (int i = 0; i < 8; i++) {
        dd[i]     = bf2f((unsigned short)dlo[i]);
        dd[i + 8] = bf2f((unsigned short)dhi[i]);
    }

    // wave-uniform trip count: max ceil(cnt/4) over wave
    int mcnt = (cnt + 3) >> 2;
#pragma unroll
    for (int m = 1; m < 64; m <<= 1) mcnt = max(mcnt, __shfl_xor(mcnt, m));

    float acc[16];
#pragma unroll
    for (int i = 0; i < 16; i++) acc[i] = 0.f;
    float swl = 0.f;

    // pipeline: prefetch this lane's edge 0 (global edge index ls)
    bool ok = (ls < cnt);
    int sidx = 0;
    if (ok) { const int p = off + ls; sidx = (p < nStage) ? ldsCsr[p] : csr_src[rs + ls]; }
    const bf16x8* xs0 = (const bf16x8*)(xnb + (size_t)sidx * HID);
    bf16x8 slo = xs0[0], shi = xs0[1];
    float nj = normv[sidx];

    for (int t = 0; t < mcnt; ++t) {
        // prefetch edge 4(t+1)+ls
        const int e2 = 4 * (t + 1) + ls;
        const bool ok2 = (e2 < cnt);
        int sidx2 = 0;
        if (ok2) {
            const int p = off + e2;
            sidx2 = (p < nStage) ? ldsCsr[p] : csr_src[rs + e2];
        }
        const bf16x8* xs2 = (const bf16x8*)(xnb + (size_t)sidx2 * HID);
        const bf16x8 slo2 = xs2[0], shi2 = xs2[1];
        const float nj2 = normv[sidx2];

        float sr[16];
#pragma unroll
        for (int i = 0; i < 8; i++) {
            sr[i]     = bf2f((unsigned short)slo[i]);
            sr[i + 8] = bf2f((unsigned short)shi[i]);
        }
        float p0 = 0.f, p1 = 0.f, p2 = 0.f, p3 = 0.f;
#pragma unroll
        for (int i = 0; i < 4; i++) {
            p0 += sr[i]      * dd[i];
            p1 += sr[i + 4]  * dd[i + 4];
            p2 += sr[i + 8]  * dd[i + 8];
            p3 += sr[i + 12] * dd[i + 12];
        }
        const float dot = (p0 + p1) + (p2 + p3);
        const float w = ok ? __expf(beta * dot - shift) : 0.f;
        swl += w;
        const float wn = w * nj;
#pragma unroll
        for (int i = 0; i < 16; i++) acc[i] += wn * sr[i];

        slo = slo2; shi = shi2; nj = nj2; ok = ok2;
    }

    // reduce acc[16] + sw across the 4-lane group (epilogue-only)
#pragma unroll
    for (int m = 1; m < 4; m <<= 1) {
#pragma unroll
        for (int i = 0; i < 16; i++) acc[i] += __shfl_xor(acc[i], m);
        swl += __shfl_xor(swl, m);
    }

    const float inv = 1.f / fmaxf(swl, 1e-16f);
    float v[16];
#pragma unroll
    for (int i = 0; i < 16; i++) v[i] = acc[i] * inv;

    if (!LAST) {
        float ss = 0.f;
#pragma unroll
        for (int i = 0; i < 16; i++) ss += v[i] * v[i];
        const float nrm = sqrtf(ss);
        const float rn  = 1.f / fmaxf(nrm, 1e-12f);
        if (alive && ls == 0) {
            bf16x8 o0, o1;
#pragma unroll
            for (int i = 0; i < 8; i++) {
                o0[i] = (short)f2bf_rtn(v[i] * rn);
                o1[i] = (short)f2bf_rtn(v[i + 8] * rn);
            }
            bf16x8* orow = (bf16x8*)(outb + (size_t)node * HID);
            orow[0] = o0; orow[1] = o1;
            out_norm[node] = nrm;
        }
    } else {
        // fused lin2 + log_softmax; lane ls computes classes [10ls, 10ls+10)
        const int j0 = ls * 10;
        float lg[10];
#pragma unroll
        for (int j = 0; j < 10; j++) lg[j] = b2s[j0 + j];
#pragma unroll
        for (int k = 0; k < HID; k++) {
            const float vk = v[k];
#pragma unroll
            for (int j = 0; j < 10; j++) lg[j] += vk * w2s[k][j0 + j];
        }
        float m = -3.0e38f;
#pragma unroll
        for (int j = 0; j < 10; j++) m = fmaxf(m, lg[j]);
        m = fmaxf(m, __shfl_xor(m, 1)); m = fmaxf(m, __shfl_xor(m, 2));
        float s = 0.f;
#pragma unroll
        for (int j = 0; j < 10; j++) s += __expf(lg[j] - m);
        s += __shfl_xor(s, 1); s += __shfl_xor(s, 2);
        const float lse = m + __logf(s);
        if (alive) {
            float* orow = out + (size_t)node * N_CLASS + j0;
#pragma unroll
            for (int j = 0; j < 10; j++) orow[j] = lg[j] - lse;
        }
    }
}

// ============================== Launch ======================================
extern "C" void kernel_launch(void* const* d_in, const int* in_sizes, int n_in,
                              void* d_out, int out_size, void* d_ws, size_t ws_size,
                              hipStream_t stream) {
    const float* x     = (const float*)d_in[0];
    const int*   ei    = (const int*)  d_in[1];   // [2][E]: row0=src, row1=dst
    const float* w1    = (const float*)d_in[2];
    const float* b1    = (const float*)d_in[3];
    const float* beta2 = (const float*)d_in[4];
    const float* w2    = (const float*)d_in[5];
    const float* b2    = (const float*)d_in[6];
    float* out = (float*)d_out;

    const int* srcp = ei;
    const int* dstp = ei + N_EDGES;

    // workspace layout (~22 MB)
    unsigned short* xnb1 = (unsigned short*)d_ws;        // [N,16] bf16 unit rows
    unsigned short* xnb2 = xnb1 + (size_t)N_NODES * HID; // [N,16] bf16
    float* norm1 = (float*)(xnb2 + (size_t)N_NODES * HID); // [N]
    float* norm2 = norm1 + N_NODES;                      // [N]
    int* row_start = (int*)(norm2 + N_NODES);            // [N]
    unsigned short* row_cnt = (unsigned short*)(row_start + N_NODES); // [N]
    int* cursor = (int*)(row_cnt + N_NODES + (N_NODES & 1)); // [NB]
    int* binned = cursor + NB + 2;                       // [NB*CAP] padded

    const int agnnGrid = (N_NODES + 63) / 64;          // 1563

    hipMemsetAsync(cursor, 0, NB * sizeof(int), stream);

    // ---- fused CSR-binning + lin1 (independent pipelines, one dispatch) ----
    k_bin_lin1<<<BIN_BLOCKS + LIN1_BLOCKS, 256, 0, stream>>>(
        srcp, dstp, cursor, binned, x, w1, b1, xnb1, norm1);

    k_csr<<<NB, 512, 0, stream>>>(cursor, binned, row_start, row_cnt);

    // ---- AGNN layers (4 lanes/node); layer2 fuses lin2+log_softmax ----
    k_agnn<0><<<agnnGrid, 256, 0, stream>>>(row_start, row_cnt, binned, xnb1,
                                            norm1, nullptr, nullptr, nullptr,
                                            nullptr, xnb2, norm2);
    k_agnn<1><<<agnnGrid, 256, 0, stream>>>(row_start, row_cnt, binned, xnb2,
                                            norm2, beta2, w2, b2,
                                            out, nullptr, nullptr);
}